// Round 13
// baseline (167.984 us; speedup 1.0000x reference)
//
#include <hip/hip_runtime.h>

#define Bn 512
#define Cn 202
#define Pn 27
#define Nn 729
#define CHn 200
#define Kn 58
#define OUTCn 64
#define CENTERn 364    // 13*27+13
#define NCHUNK 7
#define POOLR 128      // pool rows (slots); row 127 always zero
#define ZSLOT 127
#define NCK8 28        // 8-channel chunks in padded 224 (25 written; 25..27 read-but-A-zero)
#define SPAD 864
#define WTOT (NCHUNK * 9 * OUTCn * 32)   // 129024 = 512 * 252
#define UST 20         // U row stride in shorts (40 B, 8B-aligned, 10-dword stride -> 16-bank spread)

typedef float f32x4 __attribute__((ext_vector_type(4)));
typedef f32x4 f32x4u __attribute__((aligned(4)));   // dword-aligned vector load
typedef short s16x8 __attribute__((ext_vector_type(8)));
typedef short s16x4 __attribute__((ext_vector_type(4)));

static __device__ __forceinline__ unsigned short f2bf(float f) {
  unsigned u = __float_as_uint(f);
  u += 0x7fffu + ((u >> 16) & 1u);   // RNE
  return (unsigned short)(u >> 16);
}
static __device__ __forceinline__ float bf2f(short s) {
  return __uint_as_float(((unsigned)(unsigned short)s) << 16);
}

// ---------------- Kernel PREP: mixed grid (26, B) ----------------
// ck8 in [0,25): pool-gather block for channels [8*ck8, 8*ck8+8), M-list recomputed inline
//                (no cross-kernel dependency). Writes Pool_ws[b][ck8][128][8] bf16.
// ck8 == 25:     slot-table block: writes slotpad_ws[b][841] + 252 elems of Wt2.
__global__ __launch_bounds__(256) void prep_kernel(const float* __restrict__ x,
                                                   const int* __restrict__ rand_idx,
                                                   const float* __restrict__ W,
                                                   short* __restrict__ slotpad_ws,
                                                   short* __restrict__ Wt2,
                                                   short* __restrict__ Pool_ws) {
  __shared__ float sp[Nn];
  __shared__ short M[Nn];
  __shared__ short slotS[Nn];
  __shared__ int wsum[4];
  __shared__ int s_num;
  __shared__ __align__(16) float xs[8 * Nn];   // 23,328 B (pool blocks only)

  const int ck8 = blockIdx.x;     // 0..25
  const int b = blockIdx.y;
  const int tid = threadIdx.x;
  const int lane = tid & 63;
  const int wv = tid >> 6;
  const bool is_pool = ck8 < 25;

  // stage sp plane (all blocks; L2-hit for 25 of 26)
  const float* xsp = x + ((size_t)b * Cn + CHn) * Nn;
  for (int n = tid; n < Nn; n += 256) sp[n] = xsp[n];
  // stage this block's 8 channel planes (pool blocks only; uniform branch)
  if (is_pool) {
    const float* xp = x + ((size_t)b * Cn + ck8 * 8) * Nn;
    const f32x4u* xp4 = (const f32x4u*)xp;
    f32x4* xs4 = (f32x4*)xs;
    for (int v = tid; v < (8 * Nn) / 4; v += 256) xs4[v] = xp4[v];
  }
  __syncthreads();
  float central = sp[CENTERn];
  __syncthreads();
  for (int k = tid; k < Kn; k += 256) sp[rand_idx[b * Kn + k]] = central;
  __syncthreads();

  // ---- parallel mask scan: thread owns 3 consecutive pixels
  int n0 = tid * 3;
  bool mk[3];
  int cnt = 0;
#pragma unroll
  for (int t = 0; t < 3; ++t) {
    int n = n0 + t;
    bool m = (n < Nn) && (sp[n] == central);
    mk[t] = m;
    cnt += m;
  }
  int v = cnt;
#pragma unroll
  for (int off = 1; off < 64; off <<= 1) {
    int u = __shfl_up(v, off);
    if (lane >= off) v += u;
  }
  if (lane == 63) wsum[wv] = v;
  __syncthreads();
  if (tid == 0) {
    int s = 0;
#pragma unroll
    for (int w = 0; w < 4; ++w) { int t = wsum[w]; wsum[w] = s; s += t; }
    s_num = s;
  }
  __syncthreads();
  int num = s_num;                       // >= 1 (central always masked)
  int excl = v - cnt + wsum[wv];
  int c = excl;
#pragma unroll
  for (int t = 0; t < 3; ++t) {
    int n = n0 + t;
    if (n < Nn) {
      if (mk[t]) { M[c] = (short)n; slotS[n] = (short)c; c++; }
      else { slotS[n] = (short)(~(n - c)); }   // zrank = n - (#masked before n)
    }
  }
  __syncthreads();

  if (is_pool) {
    // ---- pool gather: LDS scatter-read, contiguous 1KB/wave global store
    if (tid < POOLR) {
      const int m = tid;
      const int num1 = num < ZSLOT ? num : ZSLOT;
      bool valid = m < num1;
      int s = valid ? (int)M[m] : 0;
      s16x8 w8;
#pragma unroll
      for (int j = 0; j < 8; ++j) {
        float fv = valid ? xs[j * Nn + s] : 0.f;
        w8[j] = (short)f2bf(fv);
      }
      *(s16x8*)(Pool_ws + ((size_t)b * NCK8 + ck8) * (POOLR * 8) + m * 8) = w8;
    }
  } else {
    // ---- slot table (29x29 padded) ----
    for (int idx = tid; idx < 841; idx += 256) {
      int pi = idx / 29, pj = idx - pi * 29;
      short val = (short)ZSLOT;
      if (pi >= 1 && pi <= 27 && pj >= 1 && pj <= 27) {
        int n = (pi - 1) * Pn + (pj - 1);
        int s0 = slotS[n];
        int sv = (s0 >= 0) ? s0 : ((~s0) % num);
        if (sv > ZSLOT - 1) sv = ZSLOT - 1;   // freak-case clamp (num>127 is +6 sigma)
        val = (short)sv;
      }
      slotpad_ws[(size_t)b * SPAD + idx] = val;
    }
    // ---- weight prep: block b converts elements [252b, 252b+252)
    if (tid < 252) {
      int idx = b * 252 + tid;
      int ck = idx / (9 * OUTCn * 32);
      int rem = idx - ck * (9 * OUTCn * 32);
      int r = rem / (OUTCn * 32);
      int rem2 = rem - r * (OUTCn * 32);
      int o = rem2 >> 5;
      int cl = rem2 & 31;
      int cc = ck * 32 + cl;
      float wval = (cc < CHn) ? W[((size_t)o * CHn + cc) * 9 + r] : 0.f;
      Wt2[idx] = (short)f2bf(wval);
    }
  }
}

// ---------------- Kernel F2: fused U-GEMM + gather, o-quartered ----------------
// grid (4, 512) = (o-quarter q, batch b), 512 thr = 8 waves, 47.8 KB LDS, ONE barrier.
// Phase 1: wave wv computes U[r][slots 16wv..16wv+16][o in q*16..+16) for r=0..8.
// Phase 2: thread t accumulates pixels {t, t+512} over 9 taps from LDS; coalesced stores.
__global__ __launch_bounds__(512) void fused2_kernel(const short* __restrict__ Wt2,
                                                     const short* __restrict__ Pool_ws,
                                                     const float* __restrict__ bias,
                                                     const short* __restrict__ slotpad_ws,
                                                     float* __restrict__ y) {
  __shared__ short Slot[841];                          //  1,682 B
  __shared__ __align__(16) short Ulds[9 * POOLR * UST]; // 46,080 B
  const int q = blockIdx.x;       // o-quarter 0..3
  const int b = blockIdx.y;
  const int tid = threadIdx.x;
  const int lane = tid & 63;
  const int wv = tid >> 6;        // 0..7 = slot-tile
  const int l16 = lane & 15;
  const int kg = lane >> 4;       // 0..3

  for (int i2 = tid; i2 < 841; i2 += 512) Slot[i2] = slotpad_ws[(size_t)b * SPAD + i2];

  // ---- phase 1: U for slot-tile wv, o-quarter q, all 9 taps
  {
    const short* poolb = Pool_ws + (size_t)b * (NCK8 * POOLR * 8);
    s16x8 bv[NCHUNK];
#pragma unroll
    for (int ck = 0; ck < NCHUNK; ++ck)
      bv[ck] = *(const s16x8*)(poolb + ((size_t)(ck * 4 + kg) * POOLR + wv * 16 + l16) * 8);
#pragma unroll
    for (int r = 0; r < 9; ++r) {
      const short* wp = Wt2 + ((size_t)r * OUTCn + q * 16 + l16) * 32 + kg * 8;
      f32x4 a = (f32x4){0.f, 0.f, 0.f, 0.f};
#pragma unroll
      for (int ck = 0; ck < NCHUNK; ++ck) {
        s16x8 av = *(const s16x8*)(wp + (size_t)ck * (9 * OUTCn * 32));
        a = __builtin_amdgcn_mfma_f32_16x16x32_bf16(av, bv[ck], a, 0, 0, 0);
      }
      // D: col(slot)=l16, row(o_local)=kg*4+qq
      s16x4 u4 = {(short)f2bf(a[0]), (short)f2bf(a[1]), (short)f2bf(a[2]), (short)f2bf(a[3])};
      *(s16x4*)(Ulds + ((size_t)r * POOLR + wv * 16 + l16) * UST + kg * 4) = u4;
    }
  }
  __syncthreads();   // U + Slot ready

  // ---- phase 2: accumulate; thread t owns pixels n1=t and n2=t+512
  float accA[16], accB[16];
#pragma unroll
  for (int j = 0; j < 16; ++j) { accA[j] = 0.f; accB[j] = 0.f; }

  const int n1 = tid;
  const int pi1 = n1 / Pn, pj1 = n1 - pi1 * Pn;
  const int base1 = pi1 * 29 + pj1;
  const bool has2 = (tid + 512) < Nn;
  const int n2 = has2 ? (tid + 512) : n1;
  const int pi2 = n2 / Pn, pj2 = n2 - pi2 * Pn;
  const int base2 = pi2 * 29 + pj2;

#pragma unroll
  for (int r = 0; r < 9; ++r) {
    const int off = (r / 3) * 29 + (r % 3);
    {
      int slot = Slot[base1 + off];
      const short* u = Ulds + ((size_t)r * POOLR + slot) * UST;
#pragma unroll
      for (int seg = 0; seg < 4; ++seg) {
        s16x4 vv = *(const s16x4*)(u + seg * 4);
        accA[seg * 4 + 0] += bf2f(vv[0]);
        accA[seg * 4 + 1] += bf2f(vv[1]);
        accA[seg * 4 + 2] += bf2f(vv[2]);
        accA[seg * 4 + 3] += bf2f(vv[3]);
      }
    }
    if (has2) {
      int slot = Slot[base2 + off];
      const short* u = Ulds + ((size_t)r * POOLR + slot) * UST;
#pragma unroll
      for (int seg = 0; seg < 4; ++seg) {
        s16x4 vv = *(const s16x4*)(u + seg * 4);
        accB[seg * 4 + 0] += bf2f(vv[0]);
        accB[seg * 4 + 1] += bf2f(vv[1]);
        accB[seg * 4 + 2] += bf2f(vv[2]);
        accB[seg * 4 + 3] += bf2f(vv[3]);
      }
    }
  }

  // ---- stores: 16 o-planes, lanes consecutive n -> coalesced
  float* yb = y + ((size_t)b * OUTCn + q * 16) * Nn;
#pragma unroll
  for (int j = 0; j < 16; ++j) {
    float bo = bias[q * 16 + j];
    yb[(size_t)j * Nn + n1] = accA[j] + bo;
    if (has2) yb[(size_t)j * Nn + n2] = accB[j] + bo;
  }
}

extern "C" void kernel_launch(void* const* d_in, const int* in_sizes, int n_in,
                              void* d_out, int out_size, void* d_ws, size_t ws_size,
                              hipStream_t stream) {
  const float* x = (const float*)d_in[0];
  const float* W = (const float*)d_in[1];
  const float* bias = (const float*)d_in[2];
  const int* rand_idx = (const int*)d_in[3];
  float* y = (float*)d_out;

  char* p = (char*)d_ws;
  short* slotpad = (short*)p;   p += (size_t)Bn * SPAD * 2;               //    884,736
  short* Wt2 = (short*)p;       p += (size_t)WTOT * 2;                    //    258,048
  short* Pool_ws = (short*)p;                                             // 29,360,128

  prep_kernel<<<dim3(26, Bn), 256, 0, stream>>>(x, rand_idx, W, slotpad, Wt2, Pool_ws);
  fused2_kernel<<<dim3(4, Bn), 512, 0, stream>>>(Wt2, Pool_ws, bias, slotpad, y);
}

// Round 14
// 148.274 us; speedup vs baseline: 1.1329x; 1.1329x over previous
//
#include <hip/hip_runtime.h>

#define Bn 512
#define Cn 202
#define Pn 27
#define Nn 729
#define CHn 200
#define Kn 58
#define OUTCn 64
#define CENTERn 364    // 13*27+13
#define NCHUNK 7
#define POOLR 128      // pool rows (slots); row 127 always zero
#define ZSLOT 127
#define NCK8 28        // 8-channel chunks in padded 224 (25 written; 25..27 read-but-A-zero)
#define MCAP 128
#define SPAD 864
#define WTOT (NCHUNK * 9 * OUTCn * 32)   // 129024 = 512 * 252
#define UST 20         // U row stride in shorts (40 B, 8B-aligned, 10-dword stride -> 16-bank spread)

typedef float f32x4 __attribute__((ext_vector_type(4)));
typedef f32x4 f32x4u __attribute__((aligned(4)));   // dword-aligned vector load
typedef short s16x8 __attribute__((ext_vector_type(8)));
typedef short s16x4 __attribute__((ext_vector_type(4)));

static __device__ __forceinline__ unsigned short f2bf(float f) {
  unsigned u = __float_as_uint(f);
  u += 0x7fffu + ((u >> 16) & 1u);   // RNE
  return (unsigned short)(u >> 16);
}
static __device__ __forceinline__ float bf2f(short s) {
  return __uint_as_float(((unsigned)(unsigned short)s) << 16);
}

// ---------------- Kernel A: slot table + masked-pool list (parallel scan) + weight prep ----------------
__global__ __launch_bounds__(256) void src_kernel(const float* __restrict__ x,
                                                  const int* __restrict__ rand_idx,
                                                  const float* __restrict__ W,
                                                  short* __restrict__ slotpad_ws,
                                                  short* __restrict__ Mws,
                                                  int* __restrict__ num1_ws,
                                                  short* __restrict__ Wt2) {
  int b = blockIdx.x;
  __shared__ float sp[Nn];
  __shared__ short slotS[Nn];
  __shared__ short M[Nn];
  __shared__ int wsum[4];
  __shared__ int s_num;
  int tid = threadIdx.x;
  const int lane = tid & 63;
  const int wv = tid >> 6;
  const float* xsp = x + ((size_t)b * Cn + CHn) * Nn;
  for (int n = tid; n < Nn; n += 256) sp[n] = xsp[n];
  __syncthreads();
  float central = sp[CENTERn];
  __syncthreads();
  for (int k = tid; k < Kn; k += 256) sp[rand_idx[b * Kn + k]] = central;
  __syncthreads();

  int n0 = tid * 3;
  bool mk[3];
  int cnt = 0;
#pragma unroll
  for (int t = 0; t < 3; ++t) {
    int n = n0 + t;
    bool m = (n < Nn) && (sp[n] == central);
    mk[t] = m;
    cnt += m;
  }
  int v = cnt;
#pragma unroll
  for (int off = 1; off < 64; off <<= 1) {
    int u = __shfl_up(v, off);
    if (lane >= off) v += u;
  }
  if (lane == 63) wsum[wv] = v;
  __syncthreads();
  if (tid == 0) {
    int s = 0;
#pragma unroll
    for (int w = 0; w < 4; ++w) { int t = wsum[w]; wsum[w] = s; s += t; }
    s_num = s;
  }
  __syncthreads();
  int num = s_num;                       // >= 1 (central always masked)
  int excl = v - cnt + wsum[wv];
  int c = excl;
#pragma unroll
  for (int t = 0; t < 3; ++t) {
    int n = n0 + t;
    if (n < Nn) {
      if (mk[t]) { M[c] = (short)n; slotS[n] = (short)c; c++; }
      else { slotS[n] = (short)(~(n - c)); }   // zrank = n - (#masked before n)
    }
  }
  __syncthreads();

  int num1 = num < ZSLOT ? num : ZSLOT;
  if (tid == 0) num1_ws[b] = num1;
  for (int m = tid; m < MCAP; m += 256) Mws[(size_t)b * MCAP + m] = (m < num) ? M[m] : (short)0;
  for (int idx = tid; idx < 841; idx += 256) {
    int pi = idx / 29, pj = idx - pi * 29;
    short val = (short)ZSLOT;
    if (pi >= 1 && pi <= 27 && pj >= 1 && pj <= 27) {
      int n = (pi - 1) * Pn + (pj - 1);
      int s0 = slotS[n];
      int sv = (s0 >= 0) ? s0 : ((~s0) % num);
      if (sv > ZSLOT - 1) sv = ZSLOT - 1;   // freak-case clamp (num>127 is +6 sigma)
      val = (short)sv;
    }
    slotpad_ws[(size_t)b * SPAD + idx] = val;
  }

  // merged weight prep: block b converts elements [252b, 252b+252)
  if (tid < 252) {
    int idx = b * 252 + tid;
    int ck = idx / (9 * OUTCn * 32);
    int rem = idx - ck * (9 * OUTCn * 32);
    int r = rem / (OUTCn * 32);
    int rem2 = rem - r * (OUTCn * 32);
    int o = rem2 >> 5;
    int cl = rem2 & 31;
    int cc = ck * 32 + cl;
    float wval = (cc < CHn) ? W[((size_t)o * CHn + cc) * 9 + r] : 0.f;
    Wt2[idx] = (short)f2bf(wval);
  }
}

// ---------------- Kernel P: pool gather. grid (25, 512), vectorized + coalesced ----------------
__global__ __launch_bounds__(256) void pool_kernel(const float* __restrict__ x,
                                                   const short* __restrict__ Mws,
                                                   const int* __restrict__ num1_ws,
                                                   short* __restrict__ Pool_ws) {
  __shared__ __align__(16) float xs[8 * Nn];   // 23,328 B
  const int ck8 = blockIdx.x;     // 0..24 -> channels [8*ck8, 8*ck8+8), all < 200
  const int b = blockIdx.y;
  const int tid = threadIdx.x;
  const int c0 = ck8 * 8;
  const float* xp = x + ((size_t)b * Cn + c0) * Nn;

  const f32x4u* xp4 = (const f32x4u*)xp;
  f32x4* xs4 = (f32x4*)xs;
  for (int v = tid; v < (8 * Nn) / 4; v += 256) xs4[v] = xp4[v];
  __syncthreads();

  if (tid < POOLR) {
    const int m = tid;
    const int num1 = num1_ws[b];
    bool valid = m < num1;
    int s = valid ? (int)Mws[(size_t)b * MCAP + m] : 0;
    s16x8 w8;
#pragma unroll
    for (int j = 0; j < 8; ++j) {
      float v = valid ? xs[j * Nn + s] : 0.f;
      w8[j] = (short)f2bf(v);
    }
    *(s16x8*)(Pool_ws + ((size_t)b * NCK8 + ck8) * (POOLR * 8) + m * 8) = w8;
  }
}

// ---------------- Kernel F2: fused U-GEMM + gather, o-quartered, task-rebalanced ----------------
// grid (4, 512) = (o-quarter q, batch b), 512 thr = 8 waves, 47.8 KB LDS, ONE barrier.
// Phase 1 task split: wave = (rg = wv>>2, stp = wv&3). Wave holds B-frags for 32 slots
// (slots stp*32..+32, 56 VGPR) and loads each Wt2 fragment only for its 4-5 r's:
// Wt2 traffic/block 504 -> 252 KB (was 8x redundant), Pool 57 -> 114 KB. Same MFMA count.
// Phase 2: thread t accumulates pixels {t, t+512} over 9 taps from LDS; coalesced stores.
__global__ __launch_bounds__(512) void fused2_kernel(const short* __restrict__ Wt2,
                                                     const short* __restrict__ Pool_ws,
                                                     const float* __restrict__ bias,
                                                     const short* __restrict__ slotpad_ws,
                                                     float* __restrict__ y) {
  __shared__ short Slot[841];                          //  1,682 B
  __shared__ __align__(16) short Ulds[9 * POOLR * UST]; // 46,080 B
  const int q = blockIdx.x;       // o-quarter 0..3
  const int b = blockIdx.y;
  const int tid = threadIdx.x;
  const int lane = tid & 63;
  const int wv = tid >> 6;        // 0..7
  const int l16 = lane & 15;
  const int kg = lane >> 4;       // 0..3
  const int rg = wv >> 2;         // 0: r=0..4, 1: r=5..8
  const int stp = wv & 3;         // slot-pair: slots stp*32 .. stp*32+32

  for (int i2 = tid; i2 < 841; i2 += 512) Slot[i2] = slotpad_ws[(size_t)b * SPAD + i2];

  // ---- phase 1
  {
    const short* poolb = Pool_ws + (size_t)b * (NCK8 * POOLR * 8);
    const int slotA = stp * 32 + l16;
    s16x8 bvA[NCHUNK], bvB[NCHUNK];
#pragma unroll
    for (int ck = 0; ck < NCHUNK; ++ck) {
      const short* pb = poolb + ((size_t)(ck * 4 + kg) * POOLR + slotA) * 8;
      bvA[ck] = *(const s16x8*)(pb);
      bvB[ck] = *(const s16x8*)(pb + 16 * 8);
    }
    const int r0 = rg ? 5 : 0;
    const int nr = rg ? 4 : 5;
    for (int rr = 0; rr < nr; ++rr) {
      const int r = r0 + rr;
      const short* wp = Wt2 + ((size_t)r * OUTCn + q * 16 + l16) * 32 + kg * 8;
      f32x4 aA = (f32x4){0.f, 0.f, 0.f, 0.f};
      f32x4 aB = (f32x4){0.f, 0.f, 0.f, 0.f};
#pragma unroll
      for (int ck = 0; ck < NCHUNK; ++ck) {
        s16x8 av = *(const s16x8*)(wp + (size_t)ck * (9 * OUTCn * 32));
        aA = __builtin_amdgcn_mfma_f32_16x16x32_bf16(av, bvA[ck], aA, 0, 0, 0);
        aB = __builtin_amdgcn_mfma_f32_16x16x32_bf16(av, bvB[ck], aB, 0, 0, 0);
      }
      // D: col(slot)=l16 within tile, row(o_local)=kg*4+qq
      s16x4 uA = {(short)f2bf(aA[0]), (short)f2bf(aA[1]), (short)f2bf(aA[2]), (short)f2bf(aA[3])};
      s16x4 uB = {(short)f2bf(aB[0]), (short)f2bf(aB[1]), (short)f2bf(aB[2]), (short)f2bf(aB[3])};
      *(s16x4*)(Ulds + ((size_t)r * POOLR + slotA) * UST + kg * 4) = uA;
      *(s16x4*)(Ulds + ((size_t)r * POOLR + slotA + 16) * UST + kg * 4) = uB;
    }
  }
  __syncthreads();   // U + Slot ready

  // ---- phase 2: accumulate; thread t owns pixels n1=t and n2=t+512
  float accA[16], accB[16];
#pragma unroll
  for (int j = 0; j < 16; ++j) { accA[j] = 0.f; accB[j] = 0.f; }

  const int n1 = tid;
  const int pi1 = n1 / Pn, pj1 = n1 - pi1 * Pn;
  const int base1 = pi1 * 29 + pj1;
  const bool has2 = (tid + 512) < Nn;
  const int n2 = has2 ? (tid + 512) : n1;
  const int pi2 = n2 / Pn, pj2 = n2 - pi2 * Pn;
  const int base2 = pi2 * 29 + pj2;

#pragma unroll
  for (int r = 0; r < 9; ++r) {
    const int off = (r / 3) * 29 + (r % 3);
    {
      int slot = Slot[base1 + off];
      const short* u = Ulds + ((size_t)r * POOLR + slot) * UST;
#pragma unroll
      for (int seg = 0; seg < 4; ++seg) {
        s16x4 vv = *(const s16x4*)(u + seg * 4);
        accA[seg * 4 + 0] += bf2f(vv[0]);
        accA[seg * 4 + 1] += bf2f(vv[1]);
        accA[seg * 4 + 2] += bf2f(vv[2]);
        accA[seg * 4 + 3] += bf2f(vv[3]);
      }
    }
    if (has2) {
      int slot = Slot[base2 + off];
      const short* u = Ulds + ((size_t)r * POOLR + slot) * UST;
#pragma unroll
      for (int seg = 0; seg < 4; ++seg) {
        s16x4 vv = *(const s16x4*)(u + seg * 4);
        accB[seg * 4 + 0] += bf2f(vv[0]);
        accB[seg * 4 + 1] += bf2f(vv[1]);
        accB[seg * 4 + 2] += bf2f(vv[2]);
        accB[seg * 4 + 3] += bf2f(vv[3]);
      }
    }
  }

  // ---- stores: 16 o-planes, lanes consecutive n -> coalesced
  float* yb = y + ((size_t)b * OUTCn + q * 16) * Nn;
#pragma unroll
  for (int j = 0; j < 16; ++j) {
    float bo = bias[q * 16 + j];
    yb[(size_t)j * Nn + n1] = accA[j] + bo;
    if (has2) yb[(size_t)j * Nn + n2] = accB[j] + bo;
  }
}

extern "C" void kernel_launch(void* const* d_in, const int* in_sizes, int n_in,
                              void* d_out, int out_size, void* d_ws, size_t ws_size,
                              hipStream_t stream) {
  const float* x = (const float*)d_in[0];
  const float* W = (const float*)d_in[1];
  const float* bias = (const float*)d_in[2];
  const int* rand_idx = (const int*)d_in[3];
  float* y = (float*)d_out;

  char* p = (char*)d_ws;
  short* slotpad = (short*)p;   p += (size_t)Bn * SPAD * 2;               //    884,736
  short* Mws = (short*)p;       p += (size_t)Bn * MCAP * 2;               //    131,072
  int* num1 = (int*)p;          p += 2048;
  short* Wt2 = (short*)p;       p += (size_t)WTOT * 2;                    //    258,048
  short* Pool_ws = (short*)p;                                             // 29,360,128

  src_kernel<<<Bn, 256, 0, stream>>>(x, rand_idx, W, slotpad, Mws, num1, Wt2);
  pool_kernel<<<dim3(25, Bn), 256, 0, stream>>>(x, Mws, num1, Pool_ws);
  fused2_kernel<<<dim3(4, Bn), 512, 0, stream>>>(Wt2, Pool_ws, bias, slotpad, y);
}

// Round 15
// 147.557 us; speedup vs baseline: 1.1384x; 1.0049x over previous
//
#include <hip/hip_runtime.h>

#define Bn 512
#define Cn 202
#define Pn 27
#define Nn 729
#define CHn 200
#define Kn 58
#define OUTCn 64
#define CENTERn 364    // 13*27+13
#define NCHUNK 7
#define POOLR 128      // pool rows (slots); row 127 always zero
#define ZSLOT 127
#define NCK8 28        // 8-channel chunks in padded 224 (25 written; 25..27 read-but-A-zero)
#define MCAP 128
#define SPAD 864
#define WTOT (NCHUNK * 9 * OUTCn * 32)   // 129024 = 512 * 252
#define USTD 11        // U row stride in DWORDS (44 B; odd -> row starts cover all 32 banks)

typedef float f32x4 __attribute__((ext_vector_type(4)));
typedef f32x4 f32x4u __attribute__((aligned(4)));   // dword-aligned vector load
typedef short s16x8 __attribute__((ext_vector_type(8)));
typedef short s16x4 __attribute__((ext_vector_type(4)));

static __device__ __forceinline__ unsigned short f2bf(float f) {
  unsigned u = __float_as_uint(f);
  u += 0x7fffu + ((u >> 16) & 1u);   // RNE
  return (unsigned short)(u >> 16);
}
static __device__ __forceinline__ float bf2f(short s) {
  return __uint_as_float(((unsigned)(unsigned short)s) << 16);
}

// ---------------- Kernel A: slot table + masked-pool list (parallel scan) + weight prep ----------------
__global__ __launch_bounds__(256) void src_kernel(const float* __restrict__ x,
                                                  const int* __restrict__ rand_idx,
                                                  const float* __restrict__ W,
                                                  short* __restrict__ slotpad_ws,
                                                  short* __restrict__ Mws,
                                                  int* __restrict__ num1_ws,
                                                  short* __restrict__ Wt2) {
  int b = blockIdx.x;
  __shared__ float sp[Nn];
  __shared__ short slotS[Nn];
  __shared__ short M[Nn];
  __shared__ int wsum[4];
  __shared__ int s_num;
  int tid = threadIdx.x;
  const int lane = tid & 63;
  const int wv = tid >> 6;
  const float* xsp = x + ((size_t)b * Cn + CHn) * Nn;
  for (int n = tid; n < Nn; n += 256) sp[n] = xsp[n];
  __syncthreads();
  float central = sp[CENTERn];
  __syncthreads();
  for (int k = tid; k < Kn; k += 256) sp[rand_idx[b * Kn + k]] = central;
  __syncthreads();

  int n0 = tid * 3;
  bool mk[3];
  int cnt = 0;
#pragma unroll
  for (int t = 0; t < 3; ++t) {
    int n = n0 + t;
    bool m = (n < Nn) && (sp[n] == central);
    mk[t] = m;
    cnt += m;
  }
  int v = cnt;
#pragma unroll
  for (int off = 1; off < 64; off <<= 1) {
    int u = __shfl_up(v, off);
    if (lane >= off) v += u;
  }
  if (lane == 63) wsum[wv] = v;
  __syncthreads();
  if (tid == 0) {
    int s = 0;
#pragma unroll
    for (int w = 0; w < 4; ++w) { int t = wsum[w]; wsum[w] = s; s += t; }
    s_num = s;
  }
  __syncthreads();
  int num = s_num;                       // >= 1 (central always masked)
  int excl = v - cnt + wsum[wv];
  int c = excl;
#pragma unroll
  for (int t = 0; t < 3; ++t) {
    int n = n0 + t;
    if (n < Nn) {
      if (mk[t]) { M[c] = (short)n; slotS[n] = (short)c; c++; }
      else { slotS[n] = (short)(~(n - c)); }   // zrank = n - (#masked before n)
    }
  }
  __syncthreads();

  int num1 = num < ZSLOT ? num : ZSLOT;
  if (tid == 0) num1_ws[b] = num1;
  for (int m = tid; m < MCAP; m += 256) Mws[(size_t)b * MCAP + m] = (m < num) ? M[m] : (short)0;
  for (int idx = tid; idx < 841; idx += 256) {
    int pi = idx / 29, pj = idx - pi * 29;
    short val = (short)ZSLOT;
    if (pi >= 1 && pi <= 27 && pj >= 1 && pj <= 27) {
      int n = (pi - 1) * Pn + (pj - 1);
      int s0 = slotS[n];
      int sv = (s0 >= 0) ? s0 : ((~s0) % num);
      if (sv > ZSLOT - 1) sv = ZSLOT - 1;   // freak-case clamp (num>127 is +6 sigma)
      val = (short)sv;
    }
    slotpad_ws[(size_t)b * SPAD + idx] = val;
  }

  // merged weight prep: block b converts elements [252b, 252b+252)
  if (tid < 252) {
    int idx = b * 252 + tid;
    int ck = idx / (9 * OUTCn * 32);
    int rem = idx - ck * (9 * OUTCn * 32);
    int r = rem / (OUTCn * 32);
    int rem2 = rem - r * (OUTCn * 32);
    int o = rem2 >> 5;
    int cl = rem2 & 31;
    int cc = ck * 32 + cl;
    float wval = (cc < CHn) ? W[((size_t)o * CHn + cc) * 9 + r] : 0.f;
    Wt2[idx] = (short)f2bf(wval);
  }
}

// ---------------- Kernel P: pool gather. grid (25, 512), vectorized + coalesced ----------------
__global__ __launch_bounds__(256) void pool_kernel(const float* __restrict__ x,
                                                   const short* __restrict__ Mws,
                                                   const int* __restrict__ num1_ws,
                                                   short* __restrict__ Pool_ws) {
  __shared__ __align__(16) float xs[8 * Nn];   // 23,328 B
  const int ck8 = blockIdx.x;     // 0..24 -> channels [8*ck8, 8*ck8+8), all < 200
  const int b = blockIdx.y;
  const int tid = threadIdx.x;
  const int c0 = ck8 * 8;
  const float* xp = x + ((size_t)b * Cn + c0) * Nn;

  const f32x4u* xp4 = (const f32x4u*)xp;
  f32x4* xs4 = (f32x4*)xs;
  for (int v = tid; v < (8 * Nn) / 4; v += 256) xs4[v] = xp4[v];
  __syncthreads();

  if (tid < POOLR) {
    const int m = tid;
    const int num1 = num1_ws[b];
    bool valid = m < num1;
    int s = valid ? (int)Mws[(size_t)b * MCAP + m] : 0;
    s16x8 w8;
#pragma unroll
    for (int j = 0; j < 8; ++j) {
      float v = valid ? xs[j * Nn + s] : 0.f;
      w8[j] = (short)f2bf(v);
    }
    *(s16x8*)(Pool_ws + ((size_t)b * NCK8 + ck8) * (POOLR * 8) + m * 8) = w8;
  }
}

// ---------------- Kernel F2: fused U-GEMM + gather, o-quartered, odd-stride U ----------------
// grid (4, 512) = (o-quarter q, batch b), 512 thr = 8 waves, ~52.4 KB LDS (3 blocks/CU), ONE barrier.
// U rows stored at 11-DWORD stride (odd -> random-slot row starts cover all 32 banks, ~2-way = free).
// Phase 1: wave = (rg, stp): B-frags for 32 slots, Wt2 frags only for its 4-5 r's. Dword-pair
// writes -> ds_write2_b32. Phase 2: per (pixel, tap) 8 dword reads -> ds_read2_b32, conflict-free.
__global__ __launch_bounds__(512) void fused2_kernel(const short* __restrict__ Wt2,
                                                     const short* __restrict__ Pool_ws,
                                                     const float* __restrict__ bias,
                                                     const short* __restrict__ slotpad_ws,
                                                     float* __restrict__ y) {
  __shared__ short Slot[841];                               //  1,682 B
  __shared__ __align__(16) unsigned int Ulds[9 * POOLR * USTD]; // 50,688 B
  const int q = blockIdx.x;       // o-quarter 0..3
  const int b = blockIdx.y;
  const int tid = threadIdx.x;
  const int lane = tid & 63;
  const int wv = tid >> 6;        // 0..7
  const int l16 = lane & 15;
  const int kg = lane >> 4;       // 0..3
  const int rg = wv >> 2;         // 0: r=0..4, 1: r=5..8
  const int stp = wv & 3;         // slot-pair: slots stp*32 .. stp*32+32

  for (int i2 = tid; i2 < 841; i2 += 512) Slot[i2] = slotpad_ws[(size_t)b * SPAD + i2];

  // ---- phase 1
  {
    const short* poolb = Pool_ws + (size_t)b * (NCK8 * POOLR * 8);
    const int slotA = stp * 32 + l16;
    s16x8 bvA[NCHUNK], bvB[NCHUNK];
#pragma unroll
    for (int ck = 0; ck < NCHUNK; ++ck) {
      const short* pb = poolb + ((size_t)(ck * 4 + kg) * POOLR + slotA) * 8;
      bvA[ck] = *(const s16x8*)(pb);
      bvB[ck] = *(const s16x8*)(pb + 16 * 8);
    }
    const int r0 = rg ? 5 : 0;
    const int nr = rg ? 4 : 5;
    for (int rr = 0; rr < nr; ++rr) {
      const int r = r0 + rr;
      const short* wp = Wt2 + ((size_t)r * OUTCn + q * 16 + l16) * 32 + kg * 8;
      f32x4 aA = (f32x4){0.f, 0.f, 0.f, 0.f};
      f32x4 aB = (f32x4){0.f, 0.f, 0.f, 0.f};
#pragma unroll
      for (int ck = 0; ck < NCHUNK; ++ck) {
        s16x8 av = *(const s16x8*)(wp + (size_t)ck * (9 * OUTCn * 32));
        aA = __builtin_amdgcn_mfma_f32_16x16x32_bf16(av, bvA[ck], aA, 0, 0, 0);
        aB = __builtin_amdgcn_mfma_f32_16x16x32_bf16(av, bvB[ck], aB, 0, 0, 0);
      }
      // D: col(slot)=l16 within tile, row(o_local)=kg*4+qq. Pack 4 bf16 -> 2 dwords.
      unsigned loA = ((unsigned)f2bf(aA[0])) | (((unsigned)f2bf(aA[1])) << 16);
      unsigned hiA = ((unsigned)f2bf(aA[2])) | (((unsigned)f2bf(aA[3])) << 16);
      unsigned loB = ((unsigned)f2bf(aB[0])) | (((unsigned)f2bf(aB[1])) << 16);
      unsigned hiB = ((unsigned)f2bf(aB[2])) | (((unsigned)f2bf(aB[3])) << 16);
      unsigned* uda = Ulds + ((size_t)r * POOLR + slotA) * USTD + kg * 2;
      uda[0] = loA;
      uda[1] = hiA;
      unsigned* udb = Ulds + ((size_t)r * POOLR + slotA + 16) * USTD + kg * 2;
      udb[0] = loB;
      udb[1] = hiB;
    }
  }
  __syncthreads();   // U + Slot ready

  // ---- phase 2: accumulate; thread t owns pixels n1=t and n2=t+512
  float accA[16], accB[16];
#pragma unroll
  for (int j = 0; j < 16; ++j) { accA[j] = 0.f; accB[j] = 0.f; }

  const int n1 = tid;
  const int pi1 = n1 / Pn, pj1 = n1 - pi1 * Pn;
  const int base1 = pi1 * 29 + pj1;
  const bool has2 = (tid + 512) < Nn;
  const int n2 = has2 ? (tid + 512) : n1;
  const int pi2 = n2 / Pn, pj2 = n2 - pi2 * Pn;
  const int base2 = pi2 * 29 + pj2;

#pragma unroll
  for (int r = 0; r < 9; ++r) {
    const int off = (r / 3) * 29 + (r % 3);
    {
      int slot = Slot[base1 + off];
      const unsigned* u = Ulds + ((size_t)r * POOLR + slot) * USTD;
#pragma unroll
      for (int d = 0; d < 8; ++d) {
        unsigned w = u[d];   // adjacent dwords -> ds_read2_b32; odd row stride -> no conflicts
        accA[d * 2 + 0] += __uint_as_float(w << 16);
        accA[d * 2 + 1] += __uint_as_float(w & 0xffff0000u);
      }
    }
    if (has2) {
      int slot = Slot[base2 + off];
      const unsigned* u = Ulds + ((size_t)r * POOLR + slot) * USTD;
#pragma unroll
      for (int d = 0; d < 8; ++d) {
        unsigned w = u[d];
        accB[d * 2 + 0] += __uint_as_float(w << 16);
        accB[d * 2 + 1] += __uint_as_float(w & 0xffff0000u);
      }
    }
  }

  // ---- stores: 16 o-planes, lanes consecutive n -> coalesced
  float* yb = y + ((size_t)b * OUTCn + q * 16) * Nn;
#pragma unroll
  for (int j = 0; j < 16; ++j) {
    float bo = bias[q * 16 + j];
    yb[(size_t)j * Nn + n1] = accA[j] + bo;
    if (has2) yb[(size_t)j * Nn + n2] = accB[j] + bo;
  }
}

extern "C" void kernel_launch(void* const* d_in, const int* in_sizes, int n_in,
                              void* d_out, int out_size, void* d_ws, size_t ws_size,
                              hipStream_t stream) {
  const float* x = (const float*)d_in[0];
  const float* W = (const float*)d_in[1];
  const float* bias = (const float*)d_in[2];
  const int* rand_idx = (const int*)d_in[3];
  float* y = (float*)d_out;

  char* p = (char*)d_ws;
  short* slotpad = (short*)p;   p += (size_t)Bn * SPAD * 2;               //    884,736
  short* Mws = (short*)p;       p += (size_t)Bn * MCAP * 2;               //    131,072
  int* num1 = (int*)p;          p += 2048;
  short* Wt2 = (short*)p;       p += (size_t)WTOT * 2;                    //    258,048
  short* Pool_ws = (short*)p;                                             // 29,360,128

  src_kernel<<<Bn, 256, 0, stream>>>(x, rand_idx, W, slotpad, Mws, num1, Wt2);
  pool_kernel<<<dim3(25, Bn), 256, 0, stream>>>(x, Mws, num1, Pool_ws);
  fused2_kernel<<<dim3(4, Bn), 512, 0, stream>>>(Wt2, Pool_ws, bias, slotpad, y);
}